// Round 12
// baseline (1849.059 us; speedup 1.0000x reference)
//
#include <hip/hip_runtime.h>
#include <hip/hip_bf16.h>
#include <cmath>
#include <cstdint>

// ---------------------------------------------------------------------------
// CapsuleNet forward. Round 17 (= R16 + prim z=7 -> z=14, byte-neutral TLP):
//   - prim: R11-exact staging (BM=256, BK=32, {Ah,Bh} 64 KiB dbuf,
//     zero-conflict slots, __syncthreads pipeline) with split-K z=14
//     (11x6-tap + 3x5-tap groups) -> grid 36x14=504, exactly 2 blocks/CU
//     (LDS-limited). Staged bytes IDENTICAL to z=7 (steps/block halve);
//     co-resident block covers the per-step barrier/drain exposure.
//     R7's write-explosion was L2 thrash from K-step-16 over-fetch, not
//     z=14 (atomic lines are L2-resident: ~1.2 MB/XCD).
//   - conv1 v2 (R16): W1 LDS-resident, BN=256, measured good.
//   - routing2 rwT-coalesced, pure-f16 GEMMs.
// ---------------------------------------------------------------------------

typedef _Float16 f16;
typedef _Float16 f16x8 __attribute__((ext_vector_type(8)));
typedef float    f32x4 __attribute__((ext_vector_type(4)));
typedef float    f32x16 __attribute__((ext_vector_type(16)));

__device__ __forceinline__ void dma16(const f16* g, f16* l)
{
    __builtin_amdgcn_global_load_lds(
        (const __attribute__((address_space(1))) void*)g,
        (__attribute__((address_space(3))) void*)l, 16, 0, 0);
}

// ------------------------- conv1 weight pack --------------------------------
// wpk[c][ksub][half][r][e]: value = W1[n = c*32+r][k = ksub*16+half*8+e]
// (k >= 243 zero-padded). Linear layout == desired LDS image.
__global__ void __launch_bounds__(256) w1pack(
    const float* __restrict__ w, f16* __restrict__ wpk)
{
    int idx = blockIdx.x * 256 + threadIdx.x;       // 65536
    int e    = idx & 7;
    int r    = (idx >> 3) & 31;
    int half = (idx >> 8) & 1;
    int ksub = (idx >> 9) & 15;
    int c    = idx >> 13;
    int n = c * 32 + r;
    int k = ksub * 16 + half * 8 + e;
    float v = (k < 243) ? w[n * 243 + k] : 0.f;
    wpk[idx] = (f16)v;
}

// ------------------------- prim weight: permute to [n][khw*256+c], x128 -----
__global__ void __launch_bounds__(256) transpose_w(
    const float* __restrict__ w, f16* __restrict__ whT)
{
    __shared__ float tile[5184];                  // 64 c x 81 khw
    const int n  = blockIdx.x;                    // 0..255
    const int cq = blockIdx.y;                    // 0..3
    const int t  = threadIdx.x;
    const float* wr = w + (size_t)n * 20736 + cq * 5184;
    for (int i = t; i < 5184; i += 256) tile[i] = wr[i];
    __syncthreads();
    f16* oh = whT + (size_t)n * 20736 + cq * 64;
    for (int idx = t; idx < 648; idx += 256) {    // 81 khw x 8 c-groups
        int khw = idx >> 3, cg = idx & 7;
        f16x8 vh;
#pragma unroll
        for (int e = 0; e < 8; ++e)
            vh[e] = (f16)(tile[(cg * 8 + e) * 81 + khw] * 128.0f);
        *(f16x8*)&oh[khw * 256 + cg * 8] = vh;
    }
}

// ------------------------- route_w transpose: [c][r][i][v] -> [c][i][r][v] --
__global__ void __launch_bounds__(128) transpose_rw(
    const float* __restrict__ rw, float* __restrict__ rwT)
{
    const int r = blockIdx.x;                     // 0..1151
    const int c = blockIdx.y;                     // 0..1
    const int t = threadIdx.x;                    // 128
    const int i = t >> 4, v = t & 15;
    float val = rw[(((size_t)c * 1152 + r) * 8 + i) * 16 + v];
    rwT[(((size_t)c * 8 + i) * 1152 + r) * 16 + v] = val;
}

// ------------------------- conv1 v2: W1-resident, BN=256, 32x32x16 ----------
// C[M=chunk*400, 256] = im2col(x)[M,256] * W1[256,256]; bias+ReLU;
// output hh = f16(16*v).
__global__ void __launch_bounds__(512, 1) conv1_mfma(
    const float* __restrict__ x,
    const f16* __restrict__ wpk,
    const float* __restrict__ bias, f16* __restrict__ hh)
{
    __shared__ __align__(16) f16 W[65536];        // 128 KiB resident
    __shared__ __align__(16) f16 Abuf[8192];      // 2 x 4096 f16
    __shared__ int otab[256];
    const int t  = threadIdx.x;
    const int m0 = blockIdx.x * 128;
    const int l  = t & 63, w = t >> 6;
    const int wm = w >> 2, wn = w & 3;
    const int r  = l & 31, half = l >> 5;

    if (t < 256) {   // otab: k -> x offset (c*784 + ky*28 + kx), -1 pads
        int k = t, off = -1;
        if (k < 243) {
            int c = k / 81, khw = k - c * 81;
            int ky = khw / 9, kx = khw - ky * 9;
            off = c * 784 + ky * 28 + kx;
        }
        otab[t] = off;
    }

    // W1 -> LDS: 16 contiguous dma16 per wave
    {
        const f16* src = wpk + w * 8192;
        f16* dst = &W[w * 8192];
#pragma unroll
        for (int i = 0; i < 16; ++i)
            dma16(src + i * 512 + l * 8, dst + i * 512);
    }

    // A staging coords (thread-static)
    int m  = m0 + (t >> 7) * 32 + (t & 31);
    int bb = m / 400, pix = m - bb * 400;
    int py = pix / 20, px = pix - py * 20;
    const float* xb = x + (size_t)bb * 2352 + py * 28 + px;
    const int koff = ((t >> 6) & 1) * 16 + ((t >> 5) & 1) * 8;

    float rx[8];
    auto gather = [&](int s) {
        int kb = s * 32 + koff;
#pragma unroll
        for (int e = 0; e < 8; ++e) {
            int off = otab[kb + e];
            rx[e] = (off >= 0) ? xb[off] : 0.f;
        }
    };

    f32x16 acc[2][2];
#pragma unroll
    for (int i = 0; i < 2; ++i)
#pragma unroll
        for (int j = 0; j < 2; ++j)
#pragma unroll
            for (int e = 0; e < 16; ++e) acc[i][j][e] = 0.f;

    __syncthreads();                              // otab ready (W landed too)
    gather(0);

    for (int s = 0; s < 8; ++s) {
        __syncthreads();                          // Abuf[s&1] free
        {
            f16x8 vh;
#pragma unroll
            for (int e = 0; e < 8; ++e) vh[e] = (f16)rx[e];
            *(f16x8*)&Abuf[(s & 1) * 4096 + t * 8] = vh;
        }
        __syncthreads();                          // writes visible
        if (s < 7) gather(s + 1);
        const f16* A = &Abuf[(s & 1) * 4096];
#pragma unroll
        for (int ks = 0; ks < 2; ++ks) {
            f16x8 ah[2], bh[2];
#pragma unroll
            for (int mf = 0; mf < 2; ++mf)
                ah[mf] = *(const f16x8*)&A[(2 * wm + mf) * 1024 + ks * 512 + l * 8];
#pragma unroll
            for (int nf = 0; nf < 2; ++nf)
                bh[nf] = *(const f16x8*)&W[(2 * wn + nf) * 8192 + (s * 2 + ks) * 512 + l * 8];
#pragma unroll
            for (int mf = 0; mf < 2; ++mf)
#pragma unroll
                for (int nf = 0; nf < 2; ++nf)
                    acc[mf][nf] = __builtin_amdgcn_mfma_f32_32x32x16_f16(
                        ah[mf], bh[nf], acc[mf][nf], 0, 0, 0);
        }
    }

    // epilogue: C/D 32x32 layout: col = lane&31, row = (reg&3)+8*(reg>>2)+4*half
    float bn[2];
#pragma unroll
    for (int nf = 0; nf < 2; ++nf)
        bn[nf] = bias[wn * 64 + nf * 32 + r];
#pragma unroll
    for (int mf = 0; mf < 2; ++mf) {
#pragma unroll
        for (int reg = 0; reg < 16; ++reg) {
            int row = (reg & 3) + 8 * (reg >> 2) + 4 * half;
            int mm  = m0 + wm * 64 + mf * 32 + row;
            size_t rowp = (size_t)mm * 256;
#pragma unroll
            for (int nf = 0; nf < 2; ++nf) {
                int n = wn * 64 + nf * 32 + r;
                float v = acc[mf][nf][reg] + bn[nf];
                v = fmaxf(v, 0.f) * 16.0f;        // x16 scale for prim A-side
                hh[rowp + n] = (f16)v;
            }
        }
    }
}

// ------------------------- prim conv: R11 staging, z=14, 2 blocks/CU --------
// GEMM: C[M=chunk*36, 256] += im2col(h16)[M,Kz] * W128[Kz,256], z=14 tap
// groups (11x6 + 3x5). acc = (16A)(128W) = 2048*C; epilogue /2048.
// LDS per buffer (16384 f16 = 32 KiB): Ah[0..8191] Bh[+8192],
// each 8 chunks x (32 rows x 32 k f16). Slot swizzle within a 2KB chunk:
// slot(r,c) = r + 32*((c+r)&3); dma c0=(half-(r&3))&3, c1=c0+2; frag reads
// at o0/o1 (measured 0 conflicts).
// Pipeline: {stage(next); compute(cur); __syncthreads}. 2 blocks/CU:
// the sibling block's MFMAs cover this block's barrier/drain exposure.
__global__ void __launch_bounds__(512, 2) prim_mfma256(
    const f16* __restrict__ hh,
    const f16* __restrict__ whT,
    const float* __restrict__ bias, float* __restrict__ p, int b_base)
{
    __shared__ __align__(16) f16 lds[32768];      // 64 KiB, 2 buffers a 16384
    const int t  = threadIdx.x;
    const int m0 = blockIdx.x * 256;
    const int zi = blockIdx.y;                    // 0..13
    const int s_begin = (zi < 11) ? zi * 6 : 66 + (zi - 11) * 5;
    const int s_cnt   = (zi < 11) ? 6 : 5;
    const int nsteps  = s_cnt * 8;                // K-steps of 32 channels

    const int l  = t & 63, w = t >> 6;            // wave 0..7
    const int wm = w >> 2, wn = w & 3;            // 2 x 4 wave grid
    const int r  = l & 31, half = l >> 5;

    // ---- staging lane constants: wave w stages A-chunk w and B-chunk w ----
    int m  = m0 + 32 * w + r;
    int bb = m / 36, pix = m - bb * 36;
    int py = pix / 6, px = pix - py * 6;
    const int abase = (bb * 400 + py * 40 + px * 2) * 256;   // f16 idx in hh
    const int bbase = (32 * w + r) * 20736;                  // f16 idx in whT
    const int c0 = (half - (r & 3)) & 3;          // slot-col for dma 0
    const int c1 = (c0 + 2) & 3;                  // slot-col for dma 1

    // ---- frag-read lane offsets (f16 units within 1024-f16 chunk) ----
    const int j0 = (half + r) & 3;
    const int o0 = (r + 32 * j0) * 8;             // ksub 0
    const int o1 = (r + 32 * (j0 ^ 2)) * 8;       // ksub 1

    f32x16 acc[4][2];
#pragma unroll
    for (int i = 0; i < 4; ++i)
#pragma unroll
        for (int j = 0; j < 2; ++j)
#pragma unroll
            for (int e = 0; e < 16; ++e) acc[i][j][e] = 0.f;

    auto stage = [&](int buf, int step) {
        int s  = s_begin + (step >> 3);
        int kq = step & 7;
        int ky = s / 9, kx = s - ky * 9;
        int aAdd = abase + (ky * 20 + kx) * 256 + kq * 32;
        int bAdd = bbase + s * 256 + kq * 32;
        f16* L = &lds[buf * 16384 + w * 1024];
        dma16(hh  + aAdd + c0 * 8, L);                 // Ah, b2=0
        dma16(hh  + aAdd + c1 * 8, L + 512);           // Ah, b2=1
        dma16(whT + bAdd + c0 * 8, L + 8192);          // Bh
        dma16(whT + bAdd + c1 * 8, L + 8192 + 512);
    };

    stage(0, 0);
    __syncthreads();                              // buf0 visible to all waves

    for (int ts = 0; ts < nsteps; ++ts) {
        const int buf = ts & 1;
        if (ts + 1 < nsteps) stage(buf ^ 1, ts + 1);   // prefetch next step
        __builtin_amdgcn_sched_barrier(0);             // keep DMA issue early
        const f16* LA = &lds[buf * 16384 + wm * 4096];
        const f16* LB = &lds[buf * 16384 + 8192 + wn * 2048];
        __builtin_amdgcn_s_setprio(1);
#pragma unroll
        for (int ks = 0; ks < 2; ++ks) {
            const int o = ks ? o1 : o0;
            f16x8 ah[4], bh[2];
#pragma unroll
            for (int mf = 0; mf < 4; ++mf)
                ah[mf] = *(const f16x8*)&LA[mf * 1024 + o];
#pragma unroll
            for (int nf = 0; nf < 2; ++nf)
                bh[nf] = *(const f16x8*)&LB[nf * 1024 + o];
#pragma unroll
            for (int mf = 0; mf < 4; ++mf)
#pragma unroll
                for (int nf = 0; nf < 2; ++nf)
                    acc[mf][nf] = __builtin_amdgcn_mfma_f32_32x32x16_f16(
                        ah[mf], bh[nf], acc[mf][nf], 0, 0, 0);
        }
        __builtin_amdgcn_s_setprio(0);
        __syncthreads();                               // drains DMA + reads done
    }

    // epilogue: C/D 32x32 layout: col = lane&31, row = (reg&3)+8*(reg>>2)+4*half
    float bn[2];
#pragma unroll
    for (int nf = 0; nf < 2; ++nf) {
        int n = wn * 64 + nf * 32 + r;
        bn[nf] = (zi == 0) ? bias[n] : 0.f;
    }
#pragma unroll
    for (int mf = 0; mf < 4; ++mf) {
#pragma unroll
        for (int reg = 0; reg < 16; ++reg) {
            int row = (reg & 3) + 8 * (reg >> 2) + 4 * half;
            int mm  = m0 + wm * 128 + mf * 32 + row;
            int b2  = mm / 36, pix2 = mm - b2 * 36;
            size_t rowp = (size_t)(b_base + b2) * 9216 + pix2 * 8;
#pragma unroll
            for (int nf = 0; nf < 2; ++nf) {
                int n   = wn * 64 + nf * 32 + r;
                int cap = n >> 3, vec = n & 7;
                float v = acc[mf][nf][reg] * (1.0f / 2048.0f) + bn[nf];
                atomicAdd(&p[rowp + cap * 288 + vec], v);
            }
        }
    }
}

// ------------------------- dynamic routing (register-priors) ----------------
// rwT layout: [c][i][r][v] -> q-load lane-coalesced.
__global__ void __launch_bounds__(384) routing2(
    const float* __restrict__ p, const float* __restrict__ rwT,
    float* __restrict__ caps)
{
    const int b = blockIdx.x;
    const int c = blockIdx.y;
    const int t = threadIdx.x;
    const int lane = t & 63, wid = t >> 6;
    __shared__ float redbuf[6];
    __shared__ float tred[6][16];
    __shared__ float outv[16];

    const float* pb  = p   + (size_t)b * 9216;
    const float* rwc = rwT + (size_t)c * 8 * 1152 * 16;

    float q[3][16];
    float l[3] = {0.f, 0.f, 0.f};

#pragma unroll
    for (int j = 0; j < 3; ++j) {
        int r = t + 384 * j;
        float4 p0 = *(const float4*)&pb[r * 8];
        float4 p1 = *(const float4*)&pb[r * 8 + 4];
        float pr[8] = {p0.x, p0.y, p0.z, p0.w, p1.x, p1.y, p1.z, p1.w};
#pragma unroll
        for (int v = 0; v < 16; ++v) q[j][v] = 0.f;
#pragma unroll
        for (int i = 0; i < 8; ++i) {
            const float* wrow = rwc + ((size_t)(i * 1152 + r)) * 16;
#pragma unroll
            for (int v4 = 0; v4 < 4; ++v4) {
                float4 w4 = *(const float4*)&wrow[v4 * 4];
                q[j][v4 * 4 + 0] = fmaf(pr[i], w4.x, q[j][v4 * 4 + 0]);
                q[j][v4 * 4 + 1] = fmaf(pr[i], w4.y, q[j][v4 * 4 + 1]);
                q[j][v4 * 4 + 2] = fmaf(pr[i], w4.z, q[j][v4 * 4 + 2]);
                q[j][v4 * 4 + 3] = fmaf(pr[i], w4.w, q[j][v4 * 4 + 3]);
            }
        }
    }

    for (int it = 0; it < 3; ++it) {
        float lm = fmaxf(fmaxf(l[0], l[1]), l[2]);
#pragma unroll
        for (int off = 32; off; off >>= 1) lm = fmaxf(lm, __shfl_down(lm, off, 64));
        __syncthreads();
        if (lane == 0) redbuf[wid] = lm;
        __syncthreads();
        lm = fmaxf(fmaxf(fmaxf(redbuf[0], redbuf[1]), fmaxf(redbuf[2], redbuf[3])),
                   fmaxf(redbuf[4], redbuf[5]));

        float e[3];
        float ls = 0.f;
#pragma unroll
        for (int j = 0; j < 3; ++j) { e[j] = __expf(l[j] - lm); ls += e[j]; }
#pragma unroll
        for (int off = 32; off; off >>= 1) ls += __shfl_down(ls, off, 64);
        __syncthreads();
        if (lane == 0) redbuf[wid] = ls;
        __syncthreads();
        ls = redbuf[0] + redbuf[1] + redbuf[2] + redbuf[3] + redbuf[4] + redbuf[5];
        const float inv = 1.f / ls;

        float tv[16];
#pragma unroll
        for (int v = 0; v < 16; ++v)
            tv[v] = fmaf(e[0], q[0][v], fmaf(e[1], q[1][v], e[2] * q[2][v]));
#pragma unroll
        for (int v = 0; v < 16; ++v) {
            float xv = tv[v];
#pragma unroll
            for (int off = 32; off; off >>= 1) xv += __shfl_down(xv, off, 64);
            tv[v] = xv;
        }
        __syncthreads();
        if (lane == 0) {
#pragma unroll
            for (int v = 0; v < 16; ++v) tred[wid][v] = tv[v];
        }
        __syncthreads();
        if (t < 16)
            outv[t] = (tred[0][t] + tred[1][t] + tred[2][t]
                     + tred[3][t] + tred[4][t] + tred[5][t]) * inv;
        __syncthreads();

        float s2 = 0.f;
#pragma unroll
        for (int v = 0; v < 16; ++v) s2 += outv[v] * outv[v];
        const float scale = s2 / ((1.f + s2) * sqrtf(s2));

        if (it == 2) {
            if (t < 16) caps[((size_t)b * 2 + c) * 16 + t] = scale * outv[t];
        } else {
            float ov[16];
#pragma unroll
            for (int v = 0; v < 16; ++v) ov[v] = scale * outv[v];
#pragma unroll
            for (int j = 0; j < 3; ++j) {
                float d = 0.f;
#pragma unroll
                for (int v = 0; v < 16; ++v) d = fmaf(q[j][v], ov[v], d);
                l[j] += d;
            }
        }
    }
}

// ------------------------- class softmax + argmax mask ----------------------
__global__ void __launch_bounds__(256) mask_kernel(
    const float* __restrict__ caps, float* __restrict__ cls_out,
    float* __restrict__ masked)
{
    int b = blockIdx.x * 256 + threadIdx.x;
    if (b < 1024) {
        const float* cb = caps + (size_t)b * 32;
        float n0 = 0.f, n1 = 0.f;
#pragma unroll
        for (int v = 0; v < 16; ++v) {
            n0 = fmaf(cb[v], cb[v], n0);
            n1 = fmaf(cb[16 + v], cb[16 + v], n1);
        }
        n0 = sqrtf(n0); n1 = sqrtf(n1);
        float mx = fmaxf(n0, n1);
        float e0 = expf(n0 - mx), e1 = expf(n1 - mx);
        float inv = 1.f / (e0 + e1);
        cls_out[b * 2 + 0] = e0 * inv;
        cls_out[b * 2 + 1] = e1 * inv;
        int cs = (n1 > n0) ? 1 : 0;
#pragma unroll
        for (int v = 0; v < 16; ++v) {
            masked[(size_t)b * 32 + v]      = (cs == 0) ? cb[v] : 0.f;
            masked[(size_t)b * 32 + 16 + v] = (cs == 1) ? cb[16 + v] : 0.f;
        }
    }
}

// ------------------------- decoder GEMM -------------------------------------
template<int ACT>
__global__ void __launch_bounds__(256) dense_gemm(
    const float* __restrict__ A, const float* __restrict__ Bw,
    const float* __restrict__ bias, float* __restrict__ out,
    int M, int N, int K)
{
    __shared__ __align__(16) float As[16][128];
    __shared__ __align__(16) float Bs[16][64];
    const int t  = threadIdx.x;
    const int m0 = blockIdx.x * 128, n0 = blockIdx.y * 64;
    const int tx = t & 15, ty = t >> 4;
    const int am = t >> 1;
    const int ak = (t & 1) * 8;
    const int nb = (t & 15) * 4, kb = t >> 4;

    float acc[8][4];
#pragma unroll
    for (int i = 0; i < 8; ++i)
#pragma unroll
        for (int j = 0; j < 4; ++j) acc[i][j] = 0.f;

    for (int k0i = 0; k0i < K; k0i += 16) {
        {
            const float* ap = A + (size_t)(m0 + am) * K + k0i + ak;
            float4 v0 = *(const float4*)ap;
            float4 v1 = *(const float4*)(ap + 4);
            As[ak + 0][am] = v0.x; As[ak + 1][am] = v0.y;
            As[ak + 2][am] = v0.z; As[ak + 3][am] = v0.w;
            As[ak + 4][am] = v1.x; As[ak + 5][am] = v1.y;
            As[ak + 6][am] = v1.z; As[ak + 7][am] = v1.w;
        }
        {
            int k = k0i + kb;
            int n = n0 + nb;
            float4 v4 = make_float4(0.f, 0.f, 0.f, 0.f);
            if (n + 3 < N) {
                v4 = *(const float4*)&Bw[(size_t)k * N + n];
            } else {
                float tmp[4] = {0.f, 0.f, 0.f, 0.f};
#pragma unroll
                for (int e = 0; e < 4; ++e)
                    if (n + e < N) tmp[e] = Bw[(size_t)k * N + n + e];
                v4 = make_float4(tmp[0], tmp[1], tmp[2], tmp[3]);
            }
            *(float4*)&Bs[kb][nb] = v4;
        }
        __syncthreads();
#pragma unroll
        for (int kk = 0; kk < 16; ++kk) {
            float4 a0 = *(const float4*)&As[kk][ty * 8];
            float4 a1 = *(const float4*)&As[kk][ty * 8 + 4];
            float4 b0 = *(const float4*)&Bs[kk][tx * 4];
            float av[8] = {a0.x, a0.y, a0.z, a0.w, a1.x, a1.y, a1.z, a1.w};
            float bv[4] = {b0.x, b0.y, b0.z, b0.w};
#pragma unroll
            for (int i = 0; i < 8; ++i)
#pragma unroll
                for (int j = 0; j < 4; ++j)
                    acc[i][j] = fmaf(av[i], bv[j], acc[i][j]);
        }
        __syncthreads();
    }
#pragma unroll
    for (int i = 0; i < 8; ++i) {
        int mm = m0 + ty * 8 + i;
#pragma unroll
        for (int j = 0; j < 4; ++j) {
            int n = n0 + tx * 4 + j;
            if (n < N) {
                float v = acc[i][j] + bias[n];
                v = (ACT == 0) ? fmaxf(v, 0.f) : 1.f / (1.f + expf(-v));
                out[(size_t)mm * N + n] = v;
            }
        }
    }
}

// ------------------------- host launcher ------------------------------------
extern "C" void kernel_launch(void* const* d_in, const int* in_sizes, int n_in,
                              void* d_out, int out_size, void* d_ws, size_t ws_size,
                              hipStream_t stream)
{
    const float* x       = (const float*)d_in[0];
    const float* conv1_w = (const float*)d_in[1];
    const float* conv1_b = (const float*)d_in[2];
    const float* prim_w  = (const float*)d_in[3];
    const float* prim_b  = (const float*)d_in[4];
    const float* route_w = (const float*)d_in[5];
    const float* dec_w1  = (const float*)d_in[6];
    const float* dec_b1  = (const float*)d_in[7];
    const float* dec_w2  = (const float*)d_in[8];
    const float* dec_b2  = (const float*)d_in[9];
    const float* dec_w3  = (const float*)d_in[10];
    const float* dec_b3  = (const float*)d_in[11];

    f16*   wpk1 = (f16*)d_ws;                       //   65536 halves
    f16*   whT  = wpk1 + 65536;                     // 5308416 halves
    float* rwT    = (float*)(whT + 5308416);        //  294912 f32
    float* pbuf   = rwT + 294912;                   // 9437184 f32
    float* caps   = pbuf + 9437184;
    float* masked = caps + 32768;
    float* d1     = masked + 32768;
    float* d2     = d1 + 524288;
    f16*   hbase  = (f16*)(d2 + 1048576);
    float* outF   = (float*)d_out;

    const size_t fixed_bytes = 56229888ull;
    int chunk = 64;
    const int cand[4] = {512, 256, 128, 64};
    for (int i = 0; i < 4; ++i) {
        if (fixed_bytes + (size_t)cand[i] * 204800ull <= ws_size) {
            chunk = cand[i];
            break;
        }
    }
    if (chunk > 256) chunk = 256;                   // hh sized per chunk
    f16* hh = hbase;

    // p accumulated via atomics (split-K) -> zero it
    hipMemsetAsync(pbuf, 0, 9437184ull * sizeof(float), stream);

    w1pack<<<256, 256, 0, stream>>>(conv1_w, wpk1);
    transpose_w<<<dim3(256, 4), 256, 0, stream>>>(prim_w, whT);
    transpose_rw<<<dim3(1152, 2), 128, 0, stream>>>(route_w, rwT);

    const int nchunks = 1024 / chunk;
    for (int ci = 0; ci < nchunks; ++ci) {
        const float* xin = x + (size_t)ci * chunk * 2352;
        conv1_mfma<<<chunk * 400 / 128, 512, 0, stream>>>(
            xin, wpk1, conv1_b, hh);
        prim_mfma256<<<dim3(chunk * 36 / 256, 14), 512, 0, stream>>>(
            hh, whT, prim_b, pbuf, ci * chunk);
    }

    routing2<<<dim3(1024, 2), 384, 0, stream>>>(pbuf, rwT, caps);
    mask_kernel<<<4, 256, 0, stream>>>(caps, outF, masked);

    dense_gemm<0><<<dim3(8, 8),  256, 0, stream>>>(masked, dec_w1, dec_b1, d1, 1024, 512, 32);
    dense_gemm<0><<<dim3(8, 16), 256, 0, stream>>>(d1, dec_w2, dec_b2, d2, 1024, 1024, 512);
    dense_gemm<1><<<dim3(8, 13), 256, 0, stream>>>(d2, dec_w3, dec_b3, outF + 2048, 1024, 784, 1024);
}

// Round 13
// 1177.465 us; speedup vs baseline: 1.5704x; 1.5704x over previous
//
#include <hip/hip_runtime.h>
#include <hip/hip_bf16.h>
#include <cmath>
#include <cstdint>

// ---------------------------------------------------------------------------
// CapsuleNet forward. Round 18 (= R16 + prim atomic epilogue -> partial
// stores + reduce kernel):
//   - R17's z=14 A/B isolated the epilogue: 16.5M atomicAdds ~ 3.7 cyc/atomic
//     ~ 100 us of prim's 212 us. Loop is only ~110 us.
//   - prim (EPI=1): R11-exact loop, z=7; epilogue stores raw acc to
//     part[z][mrow][n] (plain coalesced f32). reduce_p sums 7 partials,
//     *1/2048 + bias, writes p in routing layout (float4 stores). 0 atomics,
//     deterministic sum order. No pbuf memset needed.
//   - workspace: part (66 MB @chunk=256) overlaps d1/d2 (disjoint lifetime);
//     total 168.4 MB <= proven ws >= 170.65 MB (R6 evidence). Adaptive
//     fallback to atomic path (EPI=0) if ws too small.
//   - conv1 v2 (R16, W1 LDS-resident), routing2 rwT-coalesced, f16 GEMMs.
// ---------------------------------------------------------------------------

typedef _Float16 f16;
typedef _Float16 f16x8 __attribute__((ext_vector_type(8)));
typedef float    f32x4 __attribute__((ext_vector_type(4)));
typedef float    f32x16 __attribute__((ext_vector_type(16)));

__device__ __forceinline__ void dma16(const f16* g, f16* l)
{
    __builtin_amdgcn_global_load_lds(
        (const __attribute__((address_space(1))) void*)g,
        (__attribute__((address_space(3))) void*)l, 16, 0, 0);
}

// ------------------------- conv1 weight pack --------------------------------
// wpk[c][ksub][half][r][e]: value = W1[n = c*32+r][k = ksub*16+half*8+e]
__global__ void __launch_bounds__(256) w1pack(
    const float* __restrict__ w, f16* __restrict__ wpk)
{
    int idx = blockIdx.x * 256 + threadIdx.x;       // 65536
    int e    = idx & 7;
    int r    = (idx >> 3) & 31;
    int half = (idx >> 8) & 1;
    int ksub = (idx >> 9) & 15;
    int c    = idx >> 13;
    int n = c * 32 + r;
    int k = ksub * 16 + half * 8 + e;
    float v = (k < 243) ? w[n * 243 + k] : 0.f;
    wpk[idx] = (f16)v;
}

// ------------------------- prim weight: permute to [n][khw*256+c], x128 -----
__global__ void __launch_bounds__(256) transpose_w(
    const float* __restrict__ w, f16* __restrict__ whT)
{
    __shared__ float tile[5184];                  // 64 c x 81 khw
    const int n  = blockIdx.x;                    // 0..255
    const int cq = blockIdx.y;                    // 0..3
    const int t  = threadIdx.x;
    const float* wr = w + (size_t)n * 20736 + cq * 5184;
    for (int i = t; i < 5184; i += 256) tile[i] = wr[i];
    __syncthreads();
    f16* oh = whT + (size_t)n * 20736 + cq * 64;
    for (int idx = t; idx < 648; idx += 256) {    // 81 khw x 8 c-groups
        int khw = idx >> 3, cg = idx & 7;
        f16x8 vh;
#pragma unroll
        for (int e = 0; e < 8; ++e)
            vh[e] = (f16)(tile[(cg * 8 + e) * 81 + khw] * 128.0f);
        *(f16x8*)&oh[khw * 256 + cg * 8] = vh;
    }
}

// ------------------------- route_w transpose: [c][r][i][v] -> [c][i][r][v] --
__global__ void __launch_bounds__(128) transpose_rw(
    const float* __restrict__ rw, float* __restrict__ rwT)
{
    const int r = blockIdx.x;                     // 0..1151
    const int c = blockIdx.y;                     // 0..1
    const int t = threadIdx.x;                    // 128
    const int i = t >> 4, v = t & 15;
    float val = rw[(((size_t)c * 1152 + r) * 8 + i) * 16 + v];
    rwT[(((size_t)c * 8 + i) * 1152 + r) * 16 + v] = val;
}

// ------------------------- conv1 v2: W1-resident, BN=256, 32x32x16 ----------
__global__ void __launch_bounds__(512, 1) conv1_mfma(
    const float* __restrict__ x,
    const f16* __restrict__ wpk,
    const float* __restrict__ bias, f16* __restrict__ hh)
{
    __shared__ __align__(16) f16 W[65536];        // 128 KiB resident
    __shared__ __align__(16) f16 Abuf[8192];      // 2 x 4096 f16
    __shared__ int otab[256];
    const int t  = threadIdx.x;
    const int m0 = blockIdx.x * 128;
    const int l  = t & 63, w = t >> 6;
    const int wm = w >> 2, wn = w & 3;
    const int r  = l & 31, half = l >> 5;

    if (t < 256) {   // otab: k -> x offset (c*784 + ky*28 + kx), -1 pads
        int k = t, off = -1;
        if (k < 243) {
            int c = k / 81, khw = k - c * 81;
            int ky = khw / 9, kx = khw - ky * 9;
            off = c * 784 + ky * 28 + kx;
        }
        otab[t] = off;
    }

    // W1 -> LDS: 16 contiguous dma16 per wave
    {
        const f16* src = wpk + w * 8192;
        f16* dst = &W[w * 8192];
#pragma unroll
        for (int i = 0; i < 16; ++i)
            dma16(src + i * 512 + l * 8, dst + i * 512);
    }

    // A staging coords (thread-static)
    int m  = m0 + (t >> 7) * 32 + (t & 31);
    int bb = m / 400, pix = m - bb * 400;
    int py = pix / 20, px = pix - py * 20;
    const float* xb = x + (size_t)bb * 2352 + py * 28 + px;
    const int koff = ((t >> 6) & 1) * 16 + ((t >> 5) & 1) * 8;

    float rx[8];
    auto gather = [&](int s) {
        int kb = s * 32 + koff;
#pragma unroll
        for (int e = 0; e < 8; ++e) {
            int off = otab[kb + e];
            rx[e] = (off >= 0) ? xb[off] : 0.f;
        }
    };

    f32x16 acc[2][2];
#pragma unroll
    for (int i = 0; i < 2; ++i)
#pragma unroll
        for (int j = 0; j < 2; ++j)
#pragma unroll
            for (int e = 0; e < 16; ++e) acc[i][j][e] = 0.f;

    __syncthreads();                              // otab ready (W landed too)
    gather(0);

    for (int s = 0; s < 8; ++s) {
        __syncthreads();                          // Abuf[s&1] free
        {
            f16x8 vh;
#pragma unroll
            for (int e = 0; e < 8; ++e) vh[e] = (f16)rx[e];
            *(f16x8*)&Abuf[(s & 1) * 4096 + t * 8] = vh;
        }
        __syncthreads();                          // writes visible
        if (s < 7) gather(s + 1);
        const f16* A = &Abuf[(s & 1) * 4096];
#pragma unroll
        for (int ks = 0; ks < 2; ++ks) {
            f16x8 ah[2], bh[2];
#pragma unroll
            for (int mf = 0; mf < 2; ++mf)
                ah[mf] = *(const f16x8*)&A[(2 * wm + mf) * 1024 + ks * 512 + l * 8];
#pragma unroll
            for (int nf = 0; nf < 2; ++nf)
                bh[nf] = *(const f16x8*)&W[(2 * wn + nf) * 8192 + (s * 2 + ks) * 512 + l * 8];
#pragma unroll
            for (int mf = 0; mf < 2; ++mf)
#pragma unroll
                for (int nf = 0; nf < 2; ++nf)
                    acc[mf][nf] = __builtin_amdgcn_mfma_f32_32x32x16_f16(
                        ah[mf], bh[nf], acc[mf][nf], 0, 0, 0);
        }
    }

    // epilogue: C/D 32x32 layout: col = lane&31, row = (reg&3)+8*(reg>>2)+4*half
    float bn[2];
#pragma unroll
    for (int nf = 0; nf < 2; ++nf)
        bn[nf] = bias[wn * 64 + nf * 32 + r];
#pragma unroll
    for (int mf = 0; mf < 2; ++mf) {
#pragma unroll
        for (int reg = 0; reg < 16; ++reg) {
            int row = (reg & 3) + 8 * (reg >> 2) + 4 * half;
            int mm  = m0 + wm * 64 + mf * 32 + row;
            size_t rowp = (size_t)mm * 256;
#pragma unroll
            for (int nf = 0; nf < 2; ++nf) {
                int n = wn * 64 + nf * 32 + r;
                float v = acc[mf][nf][reg] + bn[nf];
                v = fmaxf(v, 0.f) * 16.0f;        // x16 scale for prim A-side
                hh[rowp + n] = (f16)v;
            }
        }
    }
}

// ------------------------- prim conv: R11 loop, templated epilogue ----------
// GEMM: C[M=rows, 256] += im2col(h16)[M,Kz] * W128[Kz,256], z=7 tap groups.
// acc = (16A)(128W) = 2048*C.
// EPI=1: store raw acc to part[zi][mrow][n] (plain coalesced f32; /2048 and
//        bias applied in reduce_p). out = part, rows = chunk*36.
// EPI=0: legacy atomicAdd into p with /2048 + bias (fallback).
// LDS per buffer (16384 f16 = 32 KiB): Ah[0..8191] Bh[+8192],
// 8 chunks x (32 rows x 32 k f16), zero-conflict slot swizzle (measured 0).
// Pipeline: {stage(next); compute(cur); __syncthreads} (measured best).
template<int EPI>
__global__ void __launch_bounds__(512, 2) prim_mfma256(
    const f16* __restrict__ hh,
    const f16* __restrict__ whT,
    const float* __restrict__ bias, float* __restrict__ out,
    int b_base, int rows)
{
    __shared__ __align__(16) f16 lds[32768];      // 64 KiB, 2 buffers a 16384
    const int t  = threadIdx.x;
    const int m0 = blockIdx.x * 256;
    const int zi = blockIdx.y;                    // 0..6
    const int s_begin = (zi < 4) ? zi * 12 : 48 + (zi - 4) * 11;
    const int s_cnt   = (zi < 4) ? 12 : 11;
    const int nsteps  = s_cnt * 8;                // K-steps of 32 channels

    const int l  = t & 63, w = t >> 6;            // wave 0..7
    const int wm = w >> 2, wn = w & 3;            // 2 x 4 wave grid
    const int r  = l & 31, half = l >> 5;

    // ---- staging lane constants: wave w stages A-chunk w and B-chunk w ----
    int m  = m0 + 32 * w + r;
    int bb = m / 36, pix = m - bb * 36;
    int py = pix / 6, px = pix - py * 6;
    const int abase = (bb * 400 + py * 40 + px * 2) * 256;   // f16 idx in hh
    const int bbase = (32 * w + r) * 20736;                  // f16 idx in whT
    const int c0 = (half - (r & 3)) & 3;          // slot-col for dma 0
    const int c1 = (c0 + 2) & 3;                  // slot-col for dma 1

    // ---- frag-read lane offsets (f16 units within 1024-f16 chunk) ----
    const int j0 = (half + r) & 3;
    const int o0 = (r + 32 * j0) * 8;             // ksub 0
    const int o1 = (r + 32 * (j0 ^ 2)) * 8;       // ksub 1

    f32x16 acc[4][2];
#pragma unroll
    for (int i = 0; i < 4; ++i)
#pragma unroll
        for (int j = 0; j < 2; ++j)
#pragma unroll
            for (int e = 0; e < 16; ++e) acc[i][j][e] = 0.f;

    auto stage = [&](int buf, int step) {
        int s  = s_begin + (step >> 3);
        int kq = step & 7;
        int ky = s / 9, kx = s - ky * 9;
        int aAdd = abase + (ky * 20 + kx) * 256 + kq * 32;
        int bAdd = bbase + s * 256 + kq * 32;
        f16* L = &lds[buf * 16384 + w * 1024];
        dma16(hh  + aAdd + c0 * 8, L);                 // Ah, b2=0
        dma16(hh  + aAdd + c1 * 8, L + 512);           // Ah, b2=1
        dma16(whT + bAdd + c0 * 8, L + 8192);          // Bh
        dma16(whT + bAdd + c1 * 8, L + 8192 + 512);
    };

    stage(0, 0);
    __syncthreads();                              // buf0 visible to all waves

    for (int ts = 0; ts < nsteps; ++ts) {
        const int buf = ts & 1;
        if (ts + 1 < nsteps) stage(buf ^ 1, ts + 1);   // prefetch next step
        __builtin_amdgcn_sched_barrier(0);             // keep DMA issue early
        const f16* LA = &lds[buf * 16384 + wm * 4096];
        const f16* LB = &lds[buf * 16384 + 8192 + wn * 2048];
        __builtin_amdgcn_s_setprio(1);
#pragma unroll
        for (int ks = 0; ks < 2; ++ks) {
            const int o = ks ? o1 : o0;
            f16x8 ah[4], bh[2];
#pragma unroll
            for (int mf = 0; mf < 4; ++mf)
                ah[mf] = *(const f16x8*)&LA[mf * 1024 + o];
#pragma unroll
            for (int nf = 0; nf < 2; ++nf)
                bh[nf] = *(const f16x8*)&LB[nf * 1024 + o];
#pragma unroll
            for (int mf = 0; mf < 4; ++mf)
#pragma unroll
                for (int nf = 0; nf < 2; ++nf)
                    acc[mf][nf] = __builtin_amdgcn_mfma_f32_32x32x16_f16(
                        ah[mf], bh[nf], acc[mf][nf], 0, 0, 0);
        }
        __builtin_amdgcn_s_setprio(0);
        __syncthreads();                               // drains DMA + reads done
    }

    if (EPI == 1) {
        // partial store: part[zi][mrow][n], raw acc (scale+bias in reduce)
        float* part = out + (size_t)zi * rows * 256;
#pragma unroll
        for (int mf = 0; mf < 4; ++mf) {
#pragma unroll
            for (int reg = 0; reg < 16; ++reg) {
                int row = (reg & 3) + 8 * (reg >> 2) + 4 * half;
                int mm  = m0 + wm * 128 + mf * 32 + row;
                size_t base = (size_t)mm * 256;
#pragma unroll
                for (int nf = 0; nf < 2; ++nf) {
                    int n = wn * 64 + nf * 32 + r;
                    part[base + n] = acc[mf][nf][reg];
                }
            }
        }
    } else {
        // legacy atomic epilogue
        float bn[2];
#pragma unroll
        for (int nf = 0; nf < 2; ++nf) {
            int n = wn * 64 + nf * 32 + r;
            bn[nf] = (zi == 0) ? bias[n] : 0.f;
        }
#pragma unroll
        for (int mf = 0; mf < 4; ++mf) {
#pragma unroll
            for (int reg = 0; reg < 16; ++reg) {
                int row = (reg & 3) + 8 * (reg >> 2) + 4 * half;
                int mm  = m0 + wm * 128 + mf * 32 + row;
                int b2  = mm / 36, pix2 = mm - b2 * 36;
                size_t rowp = (size_t)(b_base + b2) * 9216 + pix2 * 8;
#pragma unroll
                for (int nf = 0; nf < 2; ++nf) {
                    int n   = wn * 64 + nf * 32 + r;
                    int cap = n >> 3, vec = n & 7;
                    float v = acc[mf][nf][reg] * (1.0f / 2048.0f) + bn[nf];
                    atomicAdd(&out[rowp + cap * 288 + vec], v);
                }
            }
        }
    }
}

// ------------------------- reduce: sum 7 partials -> p ----------------------
// part[z][mrow][n] (rows x 256 per z). p[b][cap*288 + pix*8 + vec].
// idx -> (mrow, g): thread sums 8 consecutive n = g*8.. (cap = g), writes
// two float4 to p (contiguous 8 floats at rowp + g*288).
__global__ void __launch_bounds__(256) reduce_p(
    const float* __restrict__ part, const float* __restrict__ bias,
    float* __restrict__ p, int b_base, int rows)
{
    int idx  = blockIdx.x * 256 + threadIdx.x;    // rows*32
    int mrow = idx >> 5, g = idx & 31;
    const float* src = part + (size_t)mrow * 256 + g * 8;
    const size_t zstride = (size_t)rows * 256;
    float s[8];
#pragma unroll
    for (int e = 0; e < 8; ++e) s[e] = 0.f;
#pragma unroll
    for (int z = 0; z < 7; ++z) {
        const float* sz = src + z * zstride;
        float4 a = *(const float4*)sz;
        float4 b = *(const float4*)(sz + 4);
        s[0] += a.x; s[1] += a.y; s[2] += a.z; s[3] += a.w;
        s[4] += b.x; s[5] += b.y; s[6] += b.z; s[7] += b.w;
    }
    float4 b0 = *(const float4*)&bias[g * 8];
    float4 b1 = *(const float4*)&bias[g * 8 + 4];
    const float sc = 1.0f / 2048.0f;
    float o[8];
    o[0] = s[0] * sc + b0.x; o[1] = s[1] * sc + b0.y;
    o[2] = s[2] * sc + b0.z; o[3] = s[3] * sc + b0.w;
    o[4] = s[4] * sc + b1.x; o[5] = s[5] * sc + b1.y;
    o[6] = s[6] * sc + b1.z; o[7] = s[7] * sc + b1.w;
    int bb = mrow / 36, pix = mrow - bb * 36;
    float* dst = p + (size_t)(b_base + bb) * 9216 + pix * 8 + g * 288;
    *(float4*)dst = make_float4(o[0], o[1], o[2], o[3]);
    *(float4*)(dst + 4) = make_float4(o[4], o[5], o[6], o[7]);
}

// ------------------------- dynamic routing (register-priors) ----------------
// rwT layout: [c][i][r][v] -> q-load lane-coalesced.
__global__ void __launch_bounds__(384) routing2(
    const float* __restrict__ p, const float* __restrict__ rwT,
    float* __restrict__ caps)
{
    const int b = blockIdx.x;
    const int c = blockIdx.y;
    const int t = threadIdx.x;
    const int lane = t & 63, wid = t >> 6;
    __shared__ float redbuf[6];
    __shared__ float tred[6][16];
    __shared__ float outv[16];

    const float* pb  = p   + (size_t)b * 9216;
    const float* rwc = rwT + (size_t)c * 8 * 1152 * 16;

    float q[3][16];
    float l[3] = {0.f, 0.f, 0.f};

#pragma unroll
    for (int j = 0; j < 3; ++j) {
        int r = t + 384 * j;
        float4 p0 = *(const float4*)&pb[r * 8];
        float4 p1 = *(const float4*)&pb[r * 8 + 4];
        float pr[8] = {p0.x, p0.y, p0.z, p0.w, p1.x, p1.y, p1.z, p1.w};
#pragma unroll
        for (int v = 0; v < 16; ++v) q[j][v] = 0.f;
#pragma unroll
        for (int i = 0; i < 8; ++i) {
            const float* wrow = rwc + ((size_t)(i * 1152 + r)) * 16;
#pragma unroll
            for (int v4 = 0; v4 < 4; ++v4) {
                float4 w4 = *(const float4*)&wrow[v4 * 4];
                q[j][v4 * 4 + 0] = fmaf(pr[i], w4.x, q[j][v4 * 4 + 0]);
                q[j][v4 * 4 + 1] = fmaf(pr[i], w4.y, q[j][v4 * 4 + 1]);
                q[j][v4 * 4 + 2] = fmaf(pr[i], w4.z, q[j][v4 * 4 + 2]);
                q[j][v4 * 4 + 3] = fmaf(pr[i], w4.w, q[j][v4 * 4 + 3]);
            }
        }
    }

    for (int it = 0; it < 3; ++it) {
        float lm = fmaxf(fmaxf(l[0], l[1]), l[2]);
#pragma unroll
        for (int off = 32; off; off >>= 1) lm = fmaxf(lm, __shfl_down(lm, off, 64));
        __syncthreads();
        if (lane == 0) redbuf[wid] = lm;
        __syncthreads();
        lm = fmaxf(fmaxf(fmaxf(redbuf[0], redbuf[1]), fmaxf(redbuf[2], redbuf[3])),
                   fmaxf(redbuf[4], redbuf[5]));

        float e[3];
        float ls = 0.f;
#pragma unroll
        for (int j = 0; j < 3; ++j) { e[j] = __expf(l[j] - lm); ls += e[j]; }
#pragma unroll
        for (int off = 32; off; off >>= 1) ls += __shfl_down(ls, off, 64);
        __syncthreads();
        if (lane == 0) redbuf[wid] = ls;
        __syncthreads();
        ls = redbuf[0] + redbuf[1] + redbuf[2] + redbuf[3] + redbuf[4] + redbuf[5];
        const float inv = 1.f / ls;

        float tv[16];
#pragma unroll
        for (int v = 0; v < 16; ++v)
            tv[v] = fmaf(e[0], q[0][v], fmaf(e[1], q[1][v], e[2] * q[2][v]));
#pragma unroll
        for (int v = 0; v < 16; ++v) {
            float xv = tv[v];
#pragma unroll
            for (int off = 32; off; off >>= 1) xv += __shfl_down(xv, off, 64);
            tv[v] = xv;
        }
        __syncthreads();
        if (lane == 0) {
#pragma unroll
            for (int v = 0; v < 16; ++v) tred[wid][v] = tv[v];
        }
        __syncthreads();
        if (t < 16)
            outv[t] = (tred[0][t] + tred[1][t] + tred[2][t]
                     + tred[3][t] + tred[4][t] + tred[5][t]) * inv;
        __syncthreads();

        float s2 = 0.f;
#pragma unroll
        for (int v = 0; v < 16; ++v) s2 += outv[v] * outv[v];
        const float scale = s2 / ((1.f + s2) * sqrtf(s2));

        if (it == 2) {
            if (t < 16) caps[((size_t)b * 2 + c) * 16 + t] = scale * outv[t];
        } else {
            float ov[16];
#pragma unroll
            for (int v = 0; v < 16; ++v) ov[v] = scale * outv[v];
#pragma unroll
            for (int j = 0; j < 3; ++j) {
                float d = 0.f;
#pragma unroll
                for (int v = 0; v < 16; ++v) d = fmaf(q[j][v], ov[v], d);
                l[j] += d;
            }
        }
    }
}

// ------------------------- class softmax + argmax mask ----------------------
__global__ void __launch_bounds__(256) mask_kernel(
    const float* __restrict__ caps, float* __restrict__ cls_out,
    float* __restrict__ masked)
{
    int b = blockIdx.x * 256 + threadIdx.x;
    if (b < 1024) {
        const float* cb = caps + (size_t)b * 32;
        float n0 = 0.f, n1 = 0.f;
#pragma unroll
        for (int v = 0; v < 16; ++v) {
            n0 = fmaf(cb[v], cb[v], n0);
            n1 = fmaf(cb[16 + v], cb[16 + v], n1);
        }
        n0 = sqrtf(n0); n1 = sqrtf(n1);
        float mx = fmaxf(n0, n1);
        float e0 = expf(n0 - mx), e1 = expf(n1 - mx);
        float inv = 1.f / (e0 + e1);
        cls_out[b * 2 + 0] = e0 * inv;
        cls_out[b * 2 + 1] = e1 * inv;
        int cs = (n1 > n0) ? 1 : 0;
#pragma unroll
        for (int v = 0; v < 16; ++v) {
            masked[(size_t)b * 32 + v]      = (cs == 0) ? cb[v] : 0.f;
            masked[(size_t)b * 32 + 16 + v] = (cs == 1) ? cb[16 + v] : 0.f;
        }
    }
}

// ------------------------- decoder GEMM -------------------------------------
template<int ACT>
__global__ void __launch_bounds__(256) dense_gemm(
    const float* __restrict__ A, const float* __restrict__ Bw,
    const float* __restrict__ bias, float* __restrict__ out,
    int M, int N, int K)
{
    __shared__ __align__(16) float As[16][128];
    __shared__ __align__(16) float Bs[16][64];
    const int t  = threadIdx.x;
    const int m0 = blockIdx.x * 128, n0 = blockIdx.y * 64;
    const int tx = t & 15, ty = t >> 4;
    const int am = t >> 1;
    const int ak = (t & 1) * 8;
    const int nb = (t & 15) * 4, kb = t >> 4;

    float acc[8][4];
#pragma unroll
    for (int i = 0; i < 8; ++i)
#pragma unroll
        for (int j = 0; j < 4; ++j) acc[i][j] = 0.f;

    for (int k0i = 0; k0i < K; k0i += 16) {
        {
            const float* ap = A + (size_t)(m0 + am) * K + k0i + ak;
            float4 v0 = *(const float4*)ap;
            float4 v1 = *(const float4*)(ap + 4);
            As[ak + 0][am] = v0.x; As[ak + 1][am] = v0.y;
            As[ak + 2][am] = v0.z; As[ak + 3][am] = v0.w;
            As[ak + 4][am] = v1.x; As[ak + 5][am] = v1.y;
            As[ak + 6][am] = v1.z; As[ak + 7][am] = v1.w;
        }
        {
            int k = k0i + kb;
            int n = n0 + nb;
            float4 v4 = make_float4(0.f, 0.f, 0.f, 0.f);
            if (n + 3 < N) {
                v4 = *(const float4*)&Bw[(size_t)k * N + n];
            } else {
                float tmp[4] = {0.f, 0.f, 0.f, 0.f};
#pragma unroll
                for (int e = 0; e < 4; ++e)
                    if (n + e < N) tmp[e] = Bw[(size_t)k * N + n + e];
                v4 = make_float4(tmp[0], tmp[1], tmp[2], tmp[3]);
            }
            *(float4*)&Bs[kb][nb] = v4;
        }
        __syncthreads();
#pragma unroll
        for (int kk = 0; kk < 16; ++kk) {
            float4 a0 = *(const float4*)&As[kk][ty * 8];
            float4 a1 = *(const float4*)&As[kk][ty * 8 + 4];
            float4 b0 = *(const float4*)&Bs[kk][tx * 4];
            float av[8] = {a0.x, a0.y, a0.z, a0.w, a1.x, a1.y, a1.z, a1.w};
            float bv[4] = {b0.x, b0.y, b0.z, b0.w};
#pragma unroll
            for (int i = 0; i < 8; ++i)
#pragma unroll
                for (int j = 0; j < 4; ++j)
                    acc[i][j] = fmaf(av[i], bv[j], acc[i][j]);
        }
        __syncthreads();
    }
#pragma unroll
    for (int i = 0; i < 8; ++i) {
        int mm = m0 + ty * 8 + i;
#pragma unroll
        for (int j = 0; j < 4; ++j) {
            int n = n0 + tx * 4 + j;
            if (n < N) {
                float v = acc[i][j] + bias[n];
                v = (ACT == 0) ? fmaxf(v, 0.f) : 1.f / (1.f + expf(-v));
                out[(size_t)mm * N + n] = v;
            }
        }
    }
}

// ------------------------- host launcher ------------------------------------
extern "C" void kernel_launch(void* const* d_in, const int* in_sizes, int n_in,
                              void* d_out, int out_size, void* d_ws, size_t ws_size,
                              hipStream_t stream)
{
    const float* x       = (const float*)d_in[0];
    const float* conv1_w = (const float*)d_in[1];
    const float* conv1_b = (const float*)d_in[2];
    const float* prim_w  = (const float*)d_in[3];
    const float* prim_b  = (const float*)d_in[4];
    const float* route_w = (const float*)d_in[5];
    const float* dec_w1  = (const float*)d_in[6];
    const float* dec_b1  = (const float*)d_in[7];
    const float* dec_w2  = (const float*)d_in[8];
    const float* dec_b2  = (const float*)d_in[9];
    const float* dec_w3  = (const float*)d_in[10];
    const float* dec_b3  = (const float*)d_in[11];

    f16*   wpk1 = (f16*)d_ws;                       //   65536 halves
    f16*   whT  = wpk1 + 65536;                     // 5308416 halves
    float* rwT    = (float*)(whT + 5308416);        //  294912 f32
    float* pbuf   = rwT + 294912;                   // 9437184 f32
    float* caps   = pbuf + 9437184;                 //   32768 f32
    float* masked = caps + 32768;                   //   32768 f32
    float* uni    = masked + 32768;                 // union: part | d1+d2
    float* outF   = (float*)d_out;

    const size_t base0 = 49938432ull;               // bytes up to union start

    // New path: part = chunk*36*256*7 f32 overlapping d1/d2 (disjoint life)
    int chunk = 0;
    const int candn[3] = {256, 128, 64};
    for (int i = 0; i < 3; ++i) {
        size_t uni_b  = (size_t)candn[i] * 258048ull;           // part bytes
        if (uni_b < 6291456ull) uni_b = 6291456ull;             // >= d1+d2
        size_t need = base0 + uni_b + (size_t)candn[i] * 204800ull;
        if (need <= ws_size) { chunk = candn[i]; break; }
    }

    if (chunk) {
        float* part = uni;
        float* d1   = uni;                          // decoder reuses region
        float* d2   = d1 + 524288;
        size_t uni_f = (size_t)chunk * 64512ull;    // union floats (part)
        if (uni_f < 1572864ull) uni_f = 1572864ull;
        f16* hh = (f16*)(uni + uni_f);
        const int rows = chunk * 36;

        w1pack<<<256, 256, 0, stream>>>(conv1_w, wpk1);
        transpose_w<<<dim3(256, 4), 256, 0, stream>>>(prim_w, whT);
        transpose_rw<<<dim3(1152, 2), 128, 0, stream>>>(route_w, rwT);

        const int nchunks = 1024 / chunk;
        for (int ci = 0; ci < nchunks; ++ci) {
            const float* xin = x + (size_t)ci * chunk * 2352;
            conv1_mfma<<<chunk * 400 / 128, 512, 0, stream>>>(
                xin, wpk1, conv1_b, hh);
            prim_mfma256<1><<<dim3(rows / 256, 7), 512, 0, stream>>>(
                hh, whT, prim_b, part, 0, rows);
            reduce_p<<<rows * 32 / 256, 256, 0, stream>>>(
                part, prim_b, pbuf, ci * chunk, rows);
        }

        routing2<<<dim3(1024, 2), 384, 0, stream>>>(pbuf, rwT, caps);
        mask_kernel<<<4, 256, 0, stream>>>(caps, outF, masked);

        dense_gemm<0><<<dim3(8, 8),  256, 0, stream>>>(masked, dec_w1, dec_b1, d1, 1024, 512, 32);
        dense_gemm<0><<<dim3(8, 16), 256, 0, stream>>>(d1, dec_w2, dec_b2, d2, 1024, 1024, 512);
        dense_gemm<1><<<dim3(8, 13), 256, 0, stream>>>(d2, dec_w3, dec_b3, outF + 2048, 1024, 784, 1024);
    } else {
        // Fallback: legacy atomic path (R16)
        float* d1 = uni;
        float* d2 = d1 + 524288;
        f16* hbase = (f16*)(d2 + 1048576);
        int fchunk = 64;
        const size_t fixed_bytes = 56229888ull;
        const int cand[4] = {512, 256, 128, 64};
        for (int i = 0; i < 4; ++i) {
            if (fixed_bytes + (size_t)cand[i] * 204800ull <= ws_size) {
                fchunk = cand[i];
                break;
            }
        }
        if (fchunk > 256) fchunk = 256;
        f16* hh = hbase;

        hipMemsetAsync(pbuf, 0, 9437184ull * sizeof(float), stream);
        w1pack<<<256, 256, 0, stream>>>(conv1_w, wpk1);
        transpose_w<<<dim3(256, 4), 256, 0, stream>>>(prim_w, whT);
        transpose_rw<<<dim3(1152, 2), 128, 0, stream>>>(route_w, rwT);

        const int nchunks = 1024 / fchunk;
        for (int ci = 0; ci < nchunks; ++ci) {
            const float* xin = x + (size_t)ci * fchunk * 2352;
            conv1_mfma<<<fchunk * 400 / 128, 512, 0, stream>>>(
                xin, wpk1, conv1_b, hh);
            prim_mfma256<0><<<dim3(fchunk * 36 / 256, 7), 512, 0, stream>>>(
                hh, whT, prim_b, pbuf, ci * fchunk, fchunk * 36);
        }

        routing2<<<dim3(1024, 2), 384, 0, stream>>>(pbuf, rwT, caps);
        mask_kernel<<<4, 256, 0, stream>>>(caps, outF, masked);

        dense_gemm<0><<<dim3(8, 8),  256, 0, stream>>>(masked, dec_w1, dec_b1, d1, 1024, 512, 32);
        dense_gemm<0><<<dim3(8, 16), 256, 0, stream>>>(d1, dec_w2, dec_b2, d2, 1024, 1024, 512);
        dense_gemm<1><<<dim3(8, 13), 256, 0, stream>>>(d2, dec_w3, dec_b3, outF + 2048, 1024, 784, 1024);
    }
}